// Round 13
// baseline (34.674 us; speedup 1.0000x reference)
//
#include <hip/hip_runtime.h>
#include <math.h>

#define NB 16
#define NL 64
#define NK 32
#define NC 32
#define ND 512
#define EPSF 1e-10f

#define TILES_PER_B 36
#define PAIR_BLOCKS (NB * TILES_PER_B)   // 576 tile blocks

// att iff jsd < 5  <=>  stat = H2_i + H2_j + 64 - S < 10/ln2
#define THRS 14.426950408889634f
#define L2E  1.4426950408889634f

typedef _Float16 half2v __attribute__((ext_vector_type(2)));
typedef _Float16 half4v __attribute__((ext_vector_type(4)));
typedef _Float16 half8v __attribute__((ext_vector_type(8)));

// ws layout (floats):
//   partials : PAIR_BLOCKS*4 at float offset 0 (pad to 8192)
//   P  (f16) : 1,048,576 halves (2 MB) at float offset 8192
//   H2 (f32) : 1024 floats after P
//   h16(f16) : 524,288 halves (1 MB) after H2

__global__ void __launch_bounds__(256) softmax_kernel(
        const float* __restrict__ prior,
        const float* __restrict__ hg,
        _Float16* __restrict__ P,
        float* __restrict__ H2,
        _Float16* __restrict__ h16) {
    int bl = blockIdx.x;
    int t  = threadIdx.x;

    const float* src = prior + (size_t)bl * (NK * NC);
    float4 x = *(const float4*)(src + t * 4);
    float y0 = x.x * L2E, y1 = x.y * L2E, y2 = x.z * L2E, y3 = x.w * L2E;

    float m = fmaxf(fmaxf(y0, y1), fmaxf(y2, y3));
    #pragma unroll
    for (int w = 4; w >= 1; w >>= 1)
        m = fmaxf(m, __shfl_xor(m, w, 8));      // 8 lanes per k-row

    float e0 = exp2f(y0 - m), e1 = exp2f(y1 - m);
    float e2 = exp2f(y2 - m), e3 = exp2f(y3 - m);
    float s = e0 + e1 + e2 + e3;
    #pragma unroll
    for (int w = 4; w >= 1; w >>= 1)
        s += __shfl_xor(s, w, 8);

    float rs = 1.0f / s;
    float ls = __log2f(s);
    float p0 = e0 * rs, p1 = e1 * rs, p2 = e2 * rs, p3 = e3 * rs;
    float l0 = (y0 - m) - ls, l1 = (y1 - m) - ls;
    float l2 = (y2 - m) - ls, l3 = (y3 - m) - ls;

    half4v pv;
    pv[0] = (_Float16)fmaxf(p0, 1e-6f);
    pv[1] = (_Float16)fmaxf(p1, 1e-6f);
    pv[2] = (_Float16)fmaxf(p2, 1e-6f);
    pv[3] = (_Float16)fmaxf(p3, 1e-6f);
    *(half4v*)(P + (size_t)bl * (NK * NC) + t * 4) = pv;

    float2 hv = *(const float2*)(hg + (size_t)bl * ND + t * 2);
    half2v hh; hh[0] = (_Float16)hv.x; hh[1] = (_Float16)hv.y;
    *(half2v*)(h16 + (size_t)bl * ND + t * 2) = hh;

    float hacc = p0 * l0 + p1 * l1 + p2 * l2 + p3 * l3;
    #pragma unroll
    for (int w = 32; w >= 1; w >>= 1)
        hacc += __shfl_xor(hacc, w);
    __shared__ float red[4];
    int lane = t & 63, wib = t >> 6;
    if (lane == 0) red[wib] = hacc;
    __syncthreads();
    if (t == 0) H2[bl] = red[0] + red[1] + red[2] + red[3];
}

// 576 blocks x 512 threads (8 waves) = one 8x8 tile per block.
// Lane l of wave w owns pair (r,s)=(l>>3, l&7) and processes P-elements
// [w*128, w*128+128) and h-elements [w*64, w*64+64) of that pair:
// zero cross-lane ops and zero syncs in the hot loop (pure per-lane ILP).
// Loads are 8-way-broadcast coalesced (8 unique 16B addrs per instr) from
// L2-resident P/h16 (3 MB). One LDS reduce (8 partials) per block, then
// wave 0 classifies all 64 pairs in parallel and does one butterfly.
__global__ void __launch_bounds__(512) pair_kernel(
        const _Float16* __restrict__ P,
        const float* __restrict__ H2g,
        const _Float16* __restrict__ h16,
        float* __restrict__ partials) {
    __shared__ float sS[8][64];
    __shared__ float sM[8][64];

    int tid  = threadIdx.x;
    int lane = tid & 63;
    int wv   = tid >> 6;          // 0..7

    int b   = blockIdx.x / TILES_PER_B;
    int t36 = blockIdx.x % TILES_PER_B;
    int ti = 0, rem = t36;
    while (rem >= 8 - ti) { rem -= 8 - ti; ++ti; }
    int tj = ti + rem;
    bool diag = (ti == tj);
    int bi0 = b * NL + ti * 8;
    int bj0 = b * NL + tj * 8;

    int r = lane >> 3;   // i-row of this lane's pair
    int s = lane & 7;    // j-row

    const _Float16* Ai = P + ((size_t)(bi0 + r) << 10) + wv * 128;
    const _Float16* Bj = P + ((size_t)(bj0 + s) << 10) + wv * 128;

    float S0 = 0.f, S1 = 0.f, S2 = 0.f, S3 = 0.f;
    #pragma unroll
    for (int e = 0; e < 128; e += 16) {
        half8v a0 = *(const half8v*)(Ai + e);
        half8v b0 = *(const half8v*)(Bj + e);
        half8v a1 = *(const half8v*)(Ai + e + 8);
        half8v b1 = *(const half8v*)(Bj + e + 8);
        half8v t0 = a0 + b0;
        half8v t1 = a1 + b1;
        #pragma unroll
        for (int u = 0; u < 8; u += 2) {
            float f0 = (float)t0[u];     S0 = fmaf(f0, __log2f(f0), S0);
            float f1 = (float)t0[u + 1]; S1 = fmaf(f1, __log2f(f1), S1);
            float g0 = (float)t1[u];     S2 = fmaf(g0, __log2f(g0), S2);
            float g1 = (float)t1[u + 1]; S3 = fmaf(g1, __log2f(g1), S3);
        }
    }

    const _Float16* Hi = h16 + ((size_t)(bi0 + r) << 9) + wv * 64;
    const _Float16* Hj = h16 + ((size_t)(bj0 + s) << 9) + wv * 64;
    float M0 = 0.f, M1 = 0.f;
    #pragma unroll
    for (int e = 0; e < 64; e += 8) {
        half8v x = *(const half8v*)(Hi + e);
        half8v y = *(const half8v*)(Hj + e);
        half8v d = x - y;
        #pragma unroll
        for (int u = 0; u < 8; u += 2) {
            M0 = fmaf((float)d[u],     (float)d[u],     M0);
            M1 = fmaf((float)d[u + 1], (float)d[u + 1], M1);
        }
    }

    sS[wv][lane] = (S0 + S1) + (S2 + S3);
    sM[wv][lane] = M0 + M1;
    __syncthreads();

    if (tid < 64) {
        float S = 0.f, M = 0.f;
        #pragma unroll
        for (int w = 0; w < 8; ++w) { S += sS[w][lane]; M += sM[w][lane]; }
        float stat = H2g[bi0 + r] + H2g[bj0 + s] + 64.0f - S;
        float mse  = M * (1.0f / ND);
        float rterm = exp2f(-mse * L2E);
        bool valid = (!diag) || (s > r);
        bool isAtt = stat < THRS;
        float attN = (valid && isAtt)  ? mse   : 0.f;
        float attC = (valid && isAtt)  ? 1.f   : 0.f;
        float repN = (valid && !isAtt) ? rterm : 0.f;
        float repC = (valid && !isAtt) ? 1.f   : 0.f;
        #pragma unroll
        for (int m = 1; m <= 32; m <<= 1) {
            attN += __shfl_xor(attN, m);
            attC += __shfl_xor(attC, m);
            repN += __shfl_xor(repN, m);
            repC += __shfl_xor(repC, m);
        }
        if (lane == 0) {
            partials[blockIdx.x * 4 + 0] = attN;
            partials[blockIdx.x * 4 + 1] = attC;
            partials[blockIdx.x * 4 + 2] = repN;
            partials[blockIdx.x * 4 + 3] = repC;
        }
    }
}

__global__ void __launch_bounds__(256) finalize_kernel(
        const float* __restrict__ partials,
        float* __restrict__ out) {
    int tid = threadIdx.x;
    float a0 = 0.0f, a1 = 0.0f, a2 = 0.0f, a3 = 0.0f;
    for (int bkt = tid; bkt < PAIR_BLOCKS; bkt += 256) {
        a0 += partials[bkt * 4 + 0];
        a1 += partials[bkt * 4 + 1];
        a2 += partials[bkt * 4 + 2];
        a3 += partials[bkt * 4 + 3];
    }
    #pragma unroll
    for (int w = 32; w >= 1; w >>= 1) {
        a0 += __shfl_xor(a0, w);
        a1 += __shfl_xor(a1, w);
        a2 += __shfl_xor(a2, w);
        a3 += __shfl_xor(a3, w);
    }
    __shared__ float red[4][4];
    int lane = tid & 63, wib = tid >> 6;
    if (lane == 0) {
        red[wib][0] = a0; red[wib][1] = a1; red[wib][2] = a2; red[wib][3] = a3;
    }
    __syncthreads();
    if (tid == 0) {
        float s0 = red[0][0] + red[1][0] + red[2][0] + red[3][0];
        float s1 = red[0][1] + red[1][1] + red[2][1] + red[3][1];
        float s2 = red[0][2] + red[1][2] + red[2][2] + red[3][2];
        float s3 = red[0][3] + red[1][3] + red[2][3] + red[3][3];
        float la = s0 / (s1 + EPSF);
        float lr = s2 / (s3 + EPSF);
        out[0] = (la > 0.0f) ? la : 0.0f;
        out[1] = (lr > 0.0f) ? lr : 0.0f;
    }
}

extern "C" void kernel_launch(void* const* d_in, const int* in_sizes, int n_in,
                              void* d_out, int out_size, void* d_ws, size_t ws_size,
                              hipStream_t stream) {
    const float* prior = (const float*)d_in[0];
    const float* h     = (const float*)d_in[1];
    float* out = (float*)d_out;
    float* ws  = (float*)d_ws;

    float* partials = ws;                                    // 2304 floats
    _Float16* P = (_Float16*)(ws + 8192);                    // 1,048,576 halves
    float* H2 = ws + 8192 + 524288;                          // 1024 floats
    _Float16* h16 = (_Float16*)(ws + 8192 + 524288 + 1024);  // 524,288 halves

    softmax_kernel<<<NB * NL, 256, 0, stream>>>(prior, h, P, H2, h16);

    pair_kernel<<<PAIR_BLOCKS, 512, 0, stream>>>(P, H2, h16, partials);

    finalize_kernel<<<1, 256, 0, stream>>>(partials, out);
}